// Round 1
// baseline (260.218 us; speedup 1.0000x reference)
//
#include <hip/hip_runtime.h>

typedef unsigned short ushort_t;
typedef __attribute__((ext_vector_type(8))) short bf16x8;
typedef __attribute__((ext_vector_type(4))) short s16x4;
typedef __attribute__((ext_vector_type(4))) float f32x4;

#define BATCH 8
#define SEQ   1024
#define MEMT  8
#define LREAL 1032
#define LPAD  1152   // 9 * 128
#define DMODEL 768
#define NH    12
#define DH    64

// round-to-nearest-even fp32 -> bf16 (as raw ushort bits)
__device__ __forceinline__ ushort_t f2b(float x) {
  union { float f; unsigned u; } c; c.f = x;
  unsigned u = c.u;
  unsigned r = (u + 0x7fffu + ((u >> 16) & 1u)) >> 16;
  return (ushort_t)r;
}

#if defined(__has_builtin)
#if __has_builtin(__builtin_amdgcn_global_load_lds)
#define HAVE_GLL 1
#endif
#endif

// Stage 16 bytes per lane: global (per-lane addr) -> LDS (wave-uniform base + lane*16)
__device__ __forceinline__ void stage16(const ushort_t* g, ushort_t* lds_wave_base) {
#ifdef HAVE_GLL
  __builtin_amdgcn_global_load_lds(
      (const __attribute__((address_space(1))) unsigned int*)g,
      (__attribute__((address_space(3))) unsigned int*)lds_wave_base,
      16, 0, 0);
#else
  int lane = threadIdx.x & 63;
  *(bf16x8*)(lds_wave_base + lane * 8) = *(const bf16x8*)g;
#endif
}

// Build bf16 X with memory rows appended and zero padding to LPAD rows per batch.
__global__ __launch_bounds__(256) void build_xm(const float* __restrict__ hidden,
                                                const float* __restrict__ memv,
                                                ushort_t* __restrict__ Xm) {
  size_t idx = ((size_t)blockIdx.x * 256 + threadIdx.x) * 4;
  const size_t perB = (size_t)LPAD * DMODEL;
  int b = (int)(idx / perB);
  size_t rem = idx - (size_t)b * perB;
  int row = (int)(rem / DMODEL);
  int col = (int)(rem - (size_t)row * DMODEL);
  f32x4 v;
  if (row < SEQ) {
    v = *(const f32x4*)(hidden + ((size_t)b * SEQ + row) * DMODEL + col);
  } else if (row < LREAL) {
    v = *(const f32x4*)(memv + (size_t)(row - SEQ) * DMODEL + col);
  } else {
    v = (f32x4){0.f, 0.f, 0.f, 0.f};
  }
  s16x4 p;
  p[0] = (short)f2b(v[0]); p[1] = (short)f2b(v[1]);
  p[2] = (short)f2b(v[2]); p[3] = (short)f2b(v[3]);
  *(s16x4*)(Xm + idx) = p;
}

__global__ __launch_bounds__(256) void cast4(const float* __restrict__ src,
                                             ushort_t* __restrict__ dst, int n4) {
  int i = blockIdx.x * 256 + threadIdx.x;
  if (i >= n4) return;
  f32x4 v = *(const f32x4*)(src + (size_t)i * 4);
  s16x4 p;
  p[0] = (short)f2b(v[0]); p[1] = (short)f2b(v[1]);
  p[2] = (short)f2b(v[2]); p[3] = (short)f2b(v[3]);
  *(s16x4*)(dst + (size_t)i * 4) = p;
}

// C = A(batch rows) @ W^T + bias.  128x128 block tile, BK=32, 4 waves in 2x2.
// mode 0: out[(b*NH+h)*Rows*64 + row*64 + d]   (head-split, row-major)
// mode 1: out[(b*NH+h)*64*LPAD + d*LPAD + row] (head-split, transposed -> V^T)
__global__ __launch_bounds__(256) void gemm_qkv(const ushort_t* __restrict__ A,
                                                const ushort_t* __restrict__ W,
                                                const float* __restrict__ bias,
                                                ushort_t* __restrict__ out,
                                                int Rows, int mode) {
  __shared__ __align__(16) ushort_t As[128 * 32];
  __shared__ __align__(16) ushort_t Bs[128 * 32];
  const int tid = threadIdx.x;
  const int wave = tid >> 6, lane = tid & 63;
  const int quad = lane >> 4, l15 = lane & 15;
  const int wm = wave >> 1, wn = wave & 1;
  const int b = blockIdx.z;
  const int rowTile = blockIdx.y * 128;
  const int colTile = blockIdx.x * 128;
  const ushort_t* Ab = A + (size_t)b * LPAD * DMODEL;

  f32x4 acc[4][4] = {};

  for (int k0 = 0; k0 < DMODEL; k0 += 32) {
#pragma unroll
    for (int is = 0; is < 2; ++is) {
      int cw = is * 256 + wave * 64;  // wave-uniform chunk base
      int c = cw + lane;
      int r = c >> 2, cc = (c & 3) << 3;
      stage16(Ab + (size_t)(rowTile + r) * DMODEL + k0 + cc, As + cw * 8);
      stage16(W + (size_t)(colTile + r) * DMODEL + k0 + cc, Bs + cw * 8);
    }
    __syncthreads();
    bf16x8 af[4], bf[4];
#pragma unroll
    for (int mt = 0; mt < 4; ++mt)
      af[mt] = *(const bf16x8*)&As[(wm * 64 + mt * 16 + l15) * 32 + quad * 8];
#pragma unroll
    for (int nt = 0; nt < 4; ++nt)
      bf[nt] = *(const bf16x8*)&Bs[(wn * 64 + nt * 16 + l15) * 32 + quad * 8];
#pragma unroll
    for (int mt = 0; mt < 4; ++mt)
#pragma unroll
      for (int nt = 0; nt < 4; ++nt)
        acc[mt][nt] = __builtin_amdgcn_mfma_f32_16x16x32_bf16(af[mt], bf[nt], acc[mt][nt], 0, 0, 0);
    __syncthreads();
  }

  if (mode == 0) {
#pragma unroll
    for (int mt = 0; mt < 4; ++mt)
#pragma unroll
      for (int nt = 0; nt < 4; ++nt) {
        int row0 = rowTile + wm * 64 + mt * 16 + quad * 4;
        int col = colTile + wn * 64 + nt * 16 + l15;
        int h = col >> 6, d = col & 63;
        float bsv = bias[col];
#pragma unroll
        for (int r = 0; r < 4; ++r)
          out[(((size_t)b * NH + h) * Rows + (row0 + r)) * DH + d] = f2b(acc[mt][nt][r] + bsv);
      }
  } else {
#pragma unroll
    for (int mt = 0; mt < 4; ++mt)
#pragma unroll
      for (int nt = 0; nt < 4; ++nt) {
        int row0 = rowTile + wm * 64 + mt * 16 + quad * 4;
        int col = colTile + wn * 64 + nt * 16 + l15;
        int h = col >> 6, d = col & 63;
        float bsv = bias[col];
#pragma unroll
        for (int r = 0; r < 4; ++r)
          out[(((size_t)b * NH + h) * DH + d) * LPAD + (row0 + r)] = f2b(acc[mt][nt][r] + bsv);
      }
  }
}

// Flash attention: block = (qt, h, b), 64 q rows, 4 waves x 16 q rows each.
// Loops 17 key tiles of 64 (keys >= 1032 masked).
#define LSTR 72  // padded LDS row stride (144B: 16B-aligned, 2-way bank alias only)
__global__ __launch_bounds__(256) void attn(const ushort_t* __restrict__ Q,
                                            const ushort_t* __restrict__ K,
                                            const ushort_t* __restrict__ Vt,
                                            float* __restrict__ Out) {
  __shared__ __align__(16) ushort_t Ks[64 * LSTR];
  __shared__ __align__(16) ushort_t Vs[64 * LSTR];
  __shared__ __align__(16) ushort_t Ps[4][16 * LSTR];

  const int tid = threadIdx.x, wave = tid >> 6, lane = tid & 63;
  const int quad = lane >> 4, l15 = lane & 15;
  const int qt = blockIdx.x, h = blockIdx.y, b = blockIdx.z;

  const ushort_t* Qb = Q + ((((size_t)b * NH + h) * SEQ) + qt * 64) * DH;
  const ushort_t* Kb = K + (((size_t)b * NH + h) * LPAD) * DH;
  const ushort_t* Vb = Vt + (((size_t)b * NH + h) * DH) * LPAD;

  bf16x8 qf[2];
#pragma unroll
  for (int kk = 0; kk < 2; ++kk)
    qf[kk] = *(const bf16x8*)&Qb[(wave * 16 + l15) * DH + kk * 32 + quad * 8];

  f32x4 ob[4] = {};
  float mrow[4], lrow[4];
#pragma unroll
  for (int r = 0; r < 4; ++r) { mrow[r] = -3.0e38f; lrow[r] = 0.f; }

  for (int kt = 0; kt < 17; ++kt) {
    const int key0 = kt * 64;
    // stage K tile (64 keys x 64 d) and V^T tile (64 d x 64 l), padded stride
#pragma unroll
    for (int is = 0; is < 2; ++is) {
      int c = is * 256 + tid;
      int rr = c >> 3, cc = (c & 7) << 3;
      *(bf16x8*)&Ks[rr * LSTR + cc] = *(const bf16x8*)&Kb[(size_t)(key0 + rr) * DH + cc];
      *(bf16x8*)&Vs[rr * LSTR + cc] = *(const bf16x8*)&Vb[(size_t)rr * LPAD + key0 + cc];
    }
    __syncthreads();

    // S = Q K^T for this wave's 16 q rows x 64 keys
    f32x4 sc[4] = {};
#pragma unroll
    for (int kk = 0; kk < 2; ++kk)
#pragma unroll
      for (int nt = 0; nt < 4; ++nt) {
        bf16x8 kf = *(const bf16x8*)&Ks[(nt * 16 + l15) * LSTR + kk * 32 + quad * 8];
        sc[nt] = __builtin_amdgcn_mfma_f32_16x16x32_bf16(qf[kk], kf, sc[nt], 0, 0, 0);
      }

    // scale + mask
#pragma unroll
    for (int nt = 0; nt < 4; ++nt) {
      int key = key0 + nt * 16 + l15;
      bool valid = key < LREAL;
#pragma unroll
      for (int r = 0; r < 4; ++r)
        sc[nt][r] = valid ? sc[nt][r] * 0.125f : -3.0e38f;
    }

    // online softmax per q row (row = quad*4 + r, spread over 16 lanes of quad)
    float pr[4][4];
#pragma unroll
    for (int r = 0; r < 4; ++r) {
      float mx = fmaxf(fmaxf(sc[0][r], sc[1][r]), fmaxf(sc[2][r], sc[3][r]));
      mx = fmaxf(mx, __shfl_xor(mx, 1, 16));
      mx = fmaxf(mx, __shfl_xor(mx, 2, 16));
      mx = fmaxf(mx, __shfl_xor(mx, 4, 16));
      mx = fmaxf(mx, __shfl_xor(mx, 8, 16));
      float mnew = fmaxf(mrow[r], mx);
      float alpha = __expf(mrow[r] - mnew);
      mrow[r] = mnew;
      lrow[r] *= alpha;
#pragma unroll
      for (int dt = 0; dt < 4; ++dt) ob[dt][r] *= alpha;
      float rs = 0.f;
#pragma unroll
      for (int nt = 0; nt < 4; ++nt) {
        float p = __expf(sc[nt][r] - mnew);
        pr[nt][r] = p;
        rs += p;
      }
      rs += __shfl_xor(rs, 1, 16);
      rs += __shfl_xor(rs, 2, 16);
      rs += __shfl_xor(rs, 4, 16);
      rs += __shfl_xor(rs, 8, 16);
      lrow[r] += rs;
    }

    // P: C-layout -> LDS -> A-layout
#pragma unroll
    for (int nt = 0; nt < 4; ++nt)
#pragma unroll
      for (int r = 0; r < 4; ++r)
        Ps[wave][(quad * 4 + r) * LSTR + nt * 16 + l15] = f2b(pr[nt][r]);

    // O += P V
#pragma unroll
    for (int kk = 0; kk < 2; ++kk) {
      bf16x8 pf = *(const bf16x8*)&Ps[wave][l15 * LSTR + kk * 32 + quad * 8];
#pragma unroll
      for (int dt = 0; dt < 4; ++dt) {
        bf16x8 vf = *(const bf16x8*)&Vs[(dt * 16 + l15) * LSTR + kk * 32 + quad * 8];
        ob[dt] = __builtin_amdgcn_mfma_f32_16x16x32_bf16(pf, vf, ob[dt], 0, 0, 0);
      }
    }
    __syncthreads();
  }

  const int qrow0 = qt * 64 + wave * 16 + quad * 4;
#pragma unroll
  for (int dt = 0; dt < 4; ++dt) {
    int d = dt * 16 + l15;
#pragma unroll
    for (int r = 0; r < 4; ++r)
      Out[((size_t)b * SEQ + (qrow0 + r)) * DMODEL + h * DH + d] = ob[dt][r] / lrow[r];
  }
}

extern "C" void kernel_launch(void* const* d_in, const int* in_sizes, int n_in,
                              void* d_out, int out_size, void* d_ws, size_t ws_size,
                              hipStream_t stream) {
  const float* hidden = (const float*)d_in[0];
  const float* memv   = (const float*)d_in[1];
  const float* Wq = (const float*)d_in[2];
  const float* bq = (const float*)d_in[3];
  const float* Wk = (const float*)d_in[4];
  const float* bk = (const float*)d_in[5];
  const float* Wv = (const float*)d_in[6];
  const float* bv = (const float*)d_in[7];
  float* out = (float*)d_out;

  char* ws = (char*)d_ws;
  size_t off = 0;
  ushort_t* Xm  = (ushort_t*)(ws + off); off += (size_t)BATCH * LPAD * DMODEL * 2;
  ushort_t* Wqb = (ushort_t*)(ws + off); off += (size_t)DMODEL * DMODEL * 2;
  ushort_t* Wkb = (ushort_t*)(ws + off); off += (size_t)DMODEL * DMODEL * 2;
  ushort_t* Wvb = (ushort_t*)(ws + off); off += (size_t)DMODEL * DMODEL * 2;
  ushort_t* Qb  = (ushort_t*)(ws + off); off += (size_t)BATCH * NH * SEQ * DH * 2;
  ushort_t* Kb  = (ushort_t*)(ws + off); off += (size_t)BATCH * NH * LPAD * DH * 2;
  ushort_t* Vtb = (ushort_t*)(ws + off);

  build_xm<<<dim3(BATCH * LPAD * DMODEL / 4 / 256), 256, 0, stream>>>(hidden, memv, Xm);
  int n4 = DMODEL * DMODEL / 4;
  cast4<<<dim3((n4 + 255) / 256), 256, 0, stream>>>(Wq, Wqb, n4);
  cast4<<<dim3((n4 + 255) / 256), 256, 0, stream>>>(Wk, Wkb, n4);
  cast4<<<dim3((n4 + 255) / 256), 256, 0, stream>>>(Wv, Wvb, n4);

  gemm_qkv<<<dim3(6, 8, 8), 256, 0, stream>>>(Xm, Wqb, bq, Qb, SEQ, 0);
  gemm_qkv<<<dim3(6, 9, 8), 256, 0, stream>>>(Xm, Wkb, bk, Kb, LPAD, 0);
  gemm_qkv<<<dim3(6, 9, 8), 256, 0, stream>>>(Xm, Wvb, bv, Vtb, LPAD, 1);

  attn<<<dim3(SEQ / 64, NH, BATCH), 256, 0, stream>>>(Qb, Kb, Vtb, out);
}

// Round 2
// 198.739 us; speedup vs baseline: 1.3093x; 1.3093x over previous
//
#include <hip/hip_runtime.h>

typedef unsigned short ushort_t;
typedef __attribute__((ext_vector_type(8))) short bf16x8;
typedef __attribute__((ext_vector_type(4))) short s16x4;
typedef __attribute__((ext_vector_type(4))) float f32x4;

#define BATCH 8
#define SEQ   1024
#define MEMT  8
#define LREAL 1032
#define LPAD  1152   // 9 * 128
#define DMODEL 768
#define NH    12
#define DH    64

// round-to-nearest-even fp32 -> bf16 (raw ushort bits)
__device__ __forceinline__ ushort_t f2b(float x) {
  union { float f; unsigned u; } c; c.f = x;
  unsigned u = c.u;
  unsigned r = (u + 0x7fffu + ((u >> 16) & 1u)) >> 16;
  return (ushort_t)r;
}

#if defined(__has_builtin)
#if __has_builtin(__builtin_amdgcn_global_load_lds)
#define HAVE_GLL 1
#endif
#if __has_builtin(__builtin_amdgcn_exp2f)
#define EXP2F(x) __builtin_amdgcn_exp2f(x)
#endif
#endif
#ifndef EXP2F
#define EXP2F(x) __expf((x) * 0.6931471805599453f)
#endif

// 0.125 * log2(e): p = exp(0.125*s) = exp2(s * CEXP)
#define CEXP 0.18033688011112042f

// Stage 16 bytes/lane: global (per-lane addr) -> LDS (wave-uniform base, HW adds lane*16)
__device__ __forceinline__ void stage16(const ushort_t* g, ushort_t* lds_wave_base) {
#ifdef HAVE_GLL
  __builtin_amdgcn_global_load_lds(
      (const __attribute__((address_space(1))) unsigned int*)g,
      (__attribute__((address_space(3))) unsigned int*)lds_wave_base,
      16, 0, 0);
#else
  int lane = threadIdx.x & 63;
  *(bf16x8*)(lds_wave_base + lane * 8) = *(const bf16x8*)g;
#endif
}

// Build bf16 Xm: hidden rows, memory rows appended, zero pad to LPAD rows per batch.
__global__ __launch_bounds__(256) void build_xm(const float* __restrict__ hidden,
                                                const float* __restrict__ memv,
                                                ushort_t* __restrict__ Xm) {
  size_t idx = ((size_t)blockIdx.x * 256 + threadIdx.x) * 4;
  const size_t perB = (size_t)LPAD * DMODEL;
  int b = (int)(idx / perB);
  size_t rem = idx - (size_t)b * perB;
  int row = (int)(rem / DMODEL);
  int col = (int)(rem - (size_t)row * DMODEL);
  f32x4 v;
  if (row < SEQ) {
    v = *(const f32x4*)(hidden + ((size_t)b * SEQ + row) * DMODEL + col);
  } else if (row < LREAL) {
    v = *(const f32x4*)(memv + (size_t)(row - SEQ) * DMODEL + col);
  } else {
    v = (f32x4){0.f, 0.f, 0.f, 0.f};
  }
  s16x4 p;
  p[0] = (short)f2b(v[0]); p[1] = (short)f2b(v[1]);
  p[2] = (short)f2b(v[2]); p[3] = (short)f2b(v[3]);
  *(s16x4*)(Xm + idx) = p;
}

// Cast all 3 weight matrices in one dispatch (blockIdx.y selects).
__global__ __launch_bounds__(256) void cast3(const float* __restrict__ Wq,
                                             const float* __restrict__ Wk,
                                             const float* __restrict__ Wv,
                                             ushort_t* __restrict__ dq,
                                             ushort_t* __restrict__ dk,
                                             ushort_t* __restrict__ dv) {
  int i = blockIdx.x * 256 + threadIdx.x;  // i < 147456
  const float* src = blockIdx.y == 0 ? Wq : (blockIdx.y == 1 ? Wk : Wv);
  ushort_t* dst = blockIdx.y == 0 ? dq : (blockIdx.y == 1 ? dk : dv);
  f32x4 v = *(const f32x4*)(src + (size_t)i * 4);
  s16x4 p;
  p[0] = (short)f2b(v[0]); p[1] = (short)f2b(v[1]);
  p[2] = (short)f2b(v[2]); p[3] = (short)f2b(v[3]);
  *(s16x4*)(dst + (size_t)i * 4) = p;
}

// Fused QKV projection. One dispatch; blockIdx.y picks task:
//  y in [0,6):  V^T = Wv * Xm^T  (A=Wv rows=d, "W"=Xm cols=l) -> coalesced V^T store
//  y in [6,14): Q   = Xm * Wq^T  (rows 0..1023)
//  y in [14,23):K   = Xm * Wk^T  (rows 0..1151)
__global__ __launch_bounds__(256) void gemm_fused(
    const ushort_t* __restrict__ Xm,
    const ushort_t* __restrict__ Wqb, const ushort_t* __restrict__ Wkb,
    const ushort_t* __restrict__ Wvb,
    const float* __restrict__ bq, const float* __restrict__ bk,
    const float* __restrict__ bv,
    ushort_t* __restrict__ Qb, ushort_t* __restrict__ Kb,
    ushort_t* __restrict__ Vtb) {
  __shared__ __align__(16) ushort_t As[128 * 32];
  __shared__ __align__(16) ushort_t Bs[128 * 32];
  const int tid = threadIdx.x;
  const int wave = tid >> 6, lane = tid & 63;
  const int quad = lane >> 4, l15 = lane & 15;
  const int wm = wave >> 1, wn = wave & 1;
  const int x = blockIdx.x, y = blockIdx.y, b = blockIdx.z;
  const ushort_t* Xb = Xm + (size_t)b * LPAD * DMODEL;

  const ushort_t *A, *W;
  const float* bias;
  int task, rowTile;
  const int colTile = x * 128;
  if (y < 6) {
    task = 2; A = Wvb; W = Xb; bias = bv; rowTile = y * 128;          // x in [0,9)
  } else if (y < 14) {
    if (x >= 6) return;
    task = 0; A = Xb; W = Wqb; bias = bq; rowTile = (y - 6) * 128;
  } else {
    if (x >= 6) return;
    task = 1; A = Xb; W = Wkb; bias = bk; rowTile = (y - 14) * 128;
  }

  f32x4 acc[4][4] = {};

  for (int k0 = 0; k0 < DMODEL; k0 += 32) {
#pragma unroll
    for (int is = 0; is < 2; ++is) {
      int cw = is * 256 + wave * 64;  // wave-uniform chunk base
      int c = cw + lane;
      int r = c >> 2, cc = (c & 3) << 3;
      stage16(A + (size_t)(rowTile + r) * DMODEL + k0 + cc, As + cw * 8);
      stage16(W + (size_t)(colTile + r) * DMODEL + k0 + cc, Bs + cw * 8);
    }
    __syncthreads();
    bf16x8 af[4], bfr[4];
#pragma unroll
    for (int mt = 0; mt < 4; ++mt)
      af[mt] = *(const bf16x8*)&As[(wm * 64 + mt * 16 + l15) * 32 + quad * 8];
#pragma unroll
    for (int nt = 0; nt < 4; ++nt)
      bfr[nt] = *(const bf16x8*)&Bs[(wn * 64 + nt * 16 + l15) * 32 + quad * 8];
#pragma unroll
    for (int mt = 0; mt < 4; ++mt)
#pragma unroll
      for (int nt = 0; nt < 4; ++nt)
        acc[mt][nt] = __builtin_amdgcn_mfma_f32_16x16x32_bf16(af[mt], bfr[nt], acc[mt][nt], 0, 0, 0);
    __syncthreads();
  }

  if (task == 2) {
    // C[row=d][col=l] = V^T; bias indexed by row (d). Coalesced stores along l.
#pragma unroll
    for (int mt = 0; mt < 4; ++mt) {
      int row0 = rowTile + wm * 64 + mt * 16 + quad * 4;
      float bvr[4];
#pragma unroll
      for (int r = 0; r < 4; ++r) bvr[r] = bias[row0 + r];
#pragma unroll
      for (int nt = 0; nt < 4; ++nt) {
        int col = colTile + wn * 64 + nt * 16 + l15;
#pragma unroll
        for (int r = 0; r < 4; ++r) {
          int row = row0 + r;
          Vtb[(((size_t)b * NH + (row >> 6)) * DH + (row & 63)) * LPAD + col] =
              f2b(acc[mt][nt][r] + bvr[r]);
        }
      }
    }
  } else {
    ushort_t* out = task == 0 ? Qb : Kb;
    const int Rows = task == 0 ? SEQ : LPAD;
#pragma unroll
    for (int mt = 0; mt < 4; ++mt)
#pragma unroll
      for (int nt = 0; nt < 4; ++nt) {
        int row0 = rowTile + wm * 64 + mt * 16 + quad * 4;
        int col = colTile + wn * 64 + nt * 16 + l15;
        int h = col >> 6, d = col & 63;
        float bsv = bias[col];
#pragma unroll
        for (int r = 0; r < 4; ++r)
          out[(((size_t)b * NH + h) * Rows + (row0 + r)) * DH + d] = f2b(acc[mt][nt][r] + bsv);
      }
  }
}

// Attention, no-rescale softmax (scores bounded; exp in fp32 directly).
// Block = 128 q rows (4 waves x 32), grid (8, NH, BATCH) = 768 blocks = 3/CU.
// LDS: Ks/Vs chunked [kchunk][row64][32] (64B rows -> global_load_lds OK, 2-way alias).
// Ps per-wave 32x64 with stride 72 (write 2-way free).
__global__ __launch_bounds__(256, 3) void attn(const ushort_t* __restrict__ Q,
                                               const ushort_t* __restrict__ K,
                                               const ushort_t* __restrict__ Vt,
                                               float* __restrict__ Out) {
  __shared__ __align__(16) ushort_t Ks[4096];       // 2 chunks * 64 keys * 32
  __shared__ __align__(16) ushort_t Vs[4096];       // 2 kchunks * 64 d * 32
  __shared__ __align__(16) ushort_t Ps[4 * 2304];   // per wave: 32 rows * stride 72

  const int tid = threadIdx.x, wave = tid >> 6, lane = tid & 63;
  const int quad = lane >> 4, l15 = lane & 15;
  const int qt = blockIdx.x, h = blockIdx.y, b = blockIdx.z;

  const ushort_t* Qp = Q + (((size_t)b * NH + h) * SEQ + qt * 128) * DH;
  const ushort_t* Kp = K + ((size_t)b * NH + h) * LPAD * DH;
  const ushort_t* Vp = Vt + ((size_t)b * NH + h) * DH * LPAD;
  ushort_t* Pw = Ps + wave * 2304;

  // Q fragments: 2 m-frags x 2 k-chunks, loaded once.
  bf16x8 qf[2][2];
#pragma unroll
  for (int mt = 0; mt < 2; ++mt)
#pragma unroll
    for (int kk = 0; kk < 2; ++kk)
      qf[mt][kk] = *(const bf16x8*)&Qp[(wave * 32 + mt * 16 + l15) * DH + kk * 32 + quad * 8];

  f32x4 ob[2][4] = {};
  float lrow[2][4] = {};

  // staging address components (constant across tiles)
  const int srow = tid >> 2;            // 0..63
  const int soff = (tid & 3) << 3;      // 0,8,16,24

  for (int kt = 0; kt < 17; ++kt) {
    const int key0 = kt * 64;
#pragma unroll
    for (int p = 0; p < 2; ++p) {
      stage16(Kp + (size_t)(key0 + srow) * DH + p * 32 + soff,
              Ks + p * 2048 + wave * 512);
      stage16(Vp + (size_t)srow * LPAD + key0 + p * 32 + soff,
              Vs + p * 2048 + wave * 512);
    }
    __syncthreads();

    // S = Q K^T : 2 m-frags x 4 key-frags
    f32x4 sc[2][4] = {};
#pragma unroll
    for (int kk = 0; kk < 2; ++kk)
#pragma unroll
      for (int nt = 0; nt < 4; ++nt) {
        bf16x8 kf = *(const bf16x8*)&Ks[kk * 2048 + (nt * 16 + l15) * 32 + quad * 8];
#pragma unroll
        for (int mt = 0; mt < 2; ++mt)
          sc[mt][nt] = __builtin_amdgcn_mfma_f32_16x16x32_bf16(qf[mt][kk], kf, sc[mt][nt], 0, 0, 0);
      }

    // p = exp(s/8) directly (no max subtraction); mask pad keys in last tile.
    const bool lastTile = (kt == 16);
    const bool colValid = (l15 < 8);  // only nt==0, l15<8 valid when lastTile
#pragma unroll
    for (int mt = 0; mt < 2; ++mt)
#pragma unroll
      for (int nt = 0; nt < 4; ++nt) {
#pragma unroll
        for (int r = 0; r < 4; ++r) {
          float pv = EXP2F(sc[mt][nt][r] * CEXP);
          if (lastTile && !(nt == 0 && colValid)) pv = 0.f;
          // RNE to bf16; accumulate l from the ROUNDED value for consistency.
          union { float f; unsigned u; } cu; cu.f = pv;
          unsigned t = cu.u + 0x7fffu + ((cu.u >> 16) & 1u);
          unsigned hi = t & 0xffff0000u;
          union { unsigned u; float f; } cb; cb.u = hi;
          lrow[mt][r] += cb.f;
          Pw[(mt * 16 + quad * 4 + r) * 72 + nt * 16 + l15] = (ushort_t)(t >> 16);
        }
      }

    // O += P V
#pragma unroll
    for (int kk = 0; kk < 2; ++kk) {
      bf16x8 pf[2];
#pragma unroll
      for (int mt = 0; mt < 2; ++mt)
        pf[mt] = *(const bf16x8*)&Pw[(mt * 16 + l15) * 72 + kk * 32 + quad * 8];
#pragma unroll
      for (int dt = 0; dt < 4; ++dt) {
        bf16x8 vf = *(const bf16x8*)&Vs[kk * 2048 + (dt * 16 + l15) * 32 + quad * 8];
#pragma unroll
        for (int mt = 0; mt < 2; ++mt)
          ob[mt][dt] = __builtin_amdgcn_mfma_f32_16x16x32_bf16(pf[mt], vf, ob[mt][dt], 0, 0, 0);
      }
    }
    __syncthreads();
  }

  // one final row-sum reduction across the 16 lanes of each quad
#pragma unroll
  for (int mt = 0; mt < 2; ++mt)
#pragma unroll
    for (int r = 0; r < 4; ++r) {
      float s = lrow[mt][r];
      s += __shfl_xor(s, 1, 16);
      s += __shfl_xor(s, 2, 16);
      s += __shfl_xor(s, 4, 16);
      s += __shfl_xor(s, 8, 16);
      lrow[mt][r] = 1.0f / s;
    }

#pragma unroll
  for (int mt = 0; mt < 2; ++mt) {
    int row0 = qt * 128 + wave * 32 + mt * 16 + quad * 4;
#pragma unroll
    for (int dt = 0; dt < 4; ++dt) {
      int col = h * DH + dt * 16 + l15;
#pragma unroll
      for (int r = 0; r < 4; ++r)
        Out[((size_t)b * SEQ + row0 + r) * DMODEL + col] = ob[mt][dt][r] * lrow[mt][r];
    }
  }
}

extern "C" void kernel_launch(void* const* d_in, const int* in_sizes, int n_in,
                              void* d_out, int out_size, void* d_ws, size_t ws_size,
                              hipStream_t stream) {
  const float* hidden = (const float*)d_in[0];
  const float* memv   = (const float*)d_in[1];
  const float* Wq = (const float*)d_in[2];
  const float* bq = (const float*)d_in[3];
  const float* Wk = (const float*)d_in[4];
  const float* bk = (const float*)d_in[5];
  const float* Wv = (const float*)d_in[6];
  const float* bv = (const float*)d_in[7];
  float* out = (float*)d_out;

  char* ws = (char*)d_ws;
  size_t off = 0;
  ushort_t* Xm  = (ushort_t*)(ws + off); off += (size_t)BATCH * LPAD * DMODEL * 2;
  ushort_t* Wqb = (ushort_t*)(ws + off); off += (size_t)DMODEL * DMODEL * 2;
  ushort_t* Wkb = (ushort_t*)(ws + off); off += (size_t)DMODEL * DMODEL * 2;
  ushort_t* Wvb = (ushort_t*)(ws + off); off += (size_t)DMODEL * DMODEL * 2;
  ushort_t* Qb  = (ushort_t*)(ws + off); off += (size_t)BATCH * NH * SEQ * DH * 2;
  ushort_t* Kb  = (ushort_t*)(ws + off); off += (size_t)BATCH * NH * LPAD * DH * 2;
  ushort_t* Vtb = (ushort_t*)(ws + off);

  build_xm<<<dim3(BATCH * LPAD * DMODEL / 4 / 256), 256, 0, stream>>>(hidden, memv, Xm);
  cast3<<<dim3(DMODEL * DMODEL / 4 / 256, 3), 256, 0, stream>>>(Wq, Wk, Wv, Wqb, Wkb, Wvb);
  gemm_fused<<<dim3(9, 23, 8), 256, 0, stream>>>(Xm, Wqb, Wkb, Wvb, bq, bk, bv, Qb, Kb, Vtb);
  attn<<<dim3(SEQ / 128, NH, BATCH), 256, 0, stream>>>(Qb, Kb, Vtb, out);
}

// Round 3
// 186.125 us; speedup vs baseline: 1.3981x; 1.0678x over previous
//
#include <hip/hip_runtime.h>

typedef unsigned short ushort_t;
typedef __attribute__((ext_vector_type(8))) short bf16x8;
typedef __attribute__((ext_vector_type(4))) short s16x4;
typedef __attribute__((ext_vector_type(4))) float f32x4;

#define BATCH 8
#define SEQ   1024
#define MEMT  8
#define LREAL 1032
#define LPAD  1152   // 9 * 128
#define DMODEL 768
#define NH    12
#define DH    64

// 0.125 * log2(e): Q is pre-scaled by this in the GEMM epilogue, so attn does exp2(s) directly.
#define CEXP 0.18033688011112042f

// round-to-nearest-even fp32 -> bf16 (raw ushort bits)
__device__ __forceinline__ ushort_t f2b(float x) {
  union { float f; unsigned u; } c; c.f = x;
  unsigned u = c.u;
  unsigned r = (u + 0x7fffu + ((u >> 16) & 1u)) >> 16;
  return (ushort_t)r;
}

#if defined(__has_builtin)
#if __has_builtin(__builtin_amdgcn_global_load_lds)
#define HAVE_GLL 1
#endif
#if __has_builtin(__builtin_amdgcn_exp2f)
#define EXP2F(x) __builtin_amdgcn_exp2f(x)
#endif
#endif
#ifndef EXP2F
#define EXP2F(x) __expf((x) * 0.6931471805599453f)
#endif

// Stage 16 bytes/lane: global (per-lane addr) -> LDS (wave-uniform base, HW adds lane*16)
__device__ __forceinline__ void stage16(const ushort_t* g, ushort_t* lds_wave_base) {
#ifdef HAVE_GLL
  __builtin_amdgcn_global_load_lds(
      (const __attribute__((address_space(1))) unsigned int*)g,
      (__attribute__((address_space(3))) unsigned int*)lds_wave_base,
      16, 0, 0);
#else
  int lane = threadIdx.x & 63;
  *(bf16x8*)(lds_wave_base + lane * 8) = *(const bf16x8*)g;
#endif
}

// Merged prep: blocks [0,6912) build Xm (bf16, memory appended, zero-pad to LPAD rows);
// blocks [6912,8640) cast the 3 weight matrices.
__global__ __launch_bounds__(256) void prep(const float* __restrict__ hidden,
                                            const float* __restrict__ memv,
                                            const float* __restrict__ Wq,
                                            const float* __restrict__ Wk,
                                            const float* __restrict__ Wv,
                                            ushort_t* __restrict__ Xm,
                                            ushort_t* __restrict__ Wqb,
                                            ushort_t* __restrict__ Wkb,
                                            ushort_t* __restrict__ Wvb) {
  int bx = blockIdx.x;
  if (bx < 6912) {
    size_t idx = ((size_t)bx * 256 + threadIdx.x) * 4;
    const size_t perB = (size_t)LPAD * DMODEL;
    int b = (int)(idx / perB);
    size_t rem = idx - (size_t)b * perB;
    int row = (int)(rem / DMODEL);
    int col = (int)(rem - (size_t)row * DMODEL);
    f32x4 v;
    if (row < SEQ) {
      v = *(const f32x4*)(hidden + ((size_t)b * SEQ + row) * DMODEL + col);
    } else if (row < LREAL) {
      v = *(const f32x4*)(memv + (size_t)(row - SEQ) * DMODEL + col);
    } else {
      v = (f32x4){0.f, 0.f, 0.f, 0.f};
    }
    s16x4 p;
    p[0] = (short)f2b(v[0]); p[1] = (short)f2b(v[1]);
    p[2] = (short)f2b(v[2]); p[3] = (short)f2b(v[3]);
    *(s16x4*)(Xm + idx) = p;
  } else {
    int t = bx - 6912;            // 1728 blocks, 576 per matrix
    int m = t / 576;
    int i = (t - m * 576) * 256 + threadIdx.x;
    const float* src = m == 0 ? Wq : (m == 1 ? Wk : Wv);
    ushort_t* dst = m == 0 ? Wqb : (m == 1 ? Wkb : Wvb);
    f32x4 v = *(const f32x4*)(src + (size_t)i * 4);
    s16x4 p;
    p[0] = (short)f2b(v[0]); p[1] = (short)f2b(v[1]);
    p[2] = (short)f2b(v[2]); p[3] = (short)f2b(v[3]);
    *(s16x4*)(dst + (size_t)i * 4) = p;
  }
}

// Fused QKV projection, BK=64, XCD-pinned 1D grid of exactly 1248 blocks.
//  V blocks [0,432):  V^T = Wv * Xm^T ; pinned by (x=l-tile, b) -> Xm col-tile fetched once/XCD
//  Q blocks [432,816): Q = Xm * Wq^T  ; pinned by (y=row-tile, b) -> Xm row-tile once/XCD
//  K blocks [816,1248): K = Xm * Wk^T ; pinned by (y, b)
// Q epilogue pre-scales by CEXP.
__global__ __launch_bounds__(256) void gemm_fused(
    const ushort_t* __restrict__ Xm,
    const ushort_t* __restrict__ Wqb, const ushort_t* __restrict__ Wkb,
    const ushort_t* __restrict__ Wvb,
    const float* __restrict__ bq, const float* __restrict__ bk,
    const float* __restrict__ bv,
    ushort_t* __restrict__ Qb, ushort_t* __restrict__ Kb,
    ushort_t* __restrict__ Vtb) {
  __shared__ __align__(16) ushort_t As[2 * 4096];  // [kk][row128][32]
  __shared__ __align__(16) ushort_t Bs[2 * 4096];
  const int tid = threadIdx.x;
  const int wave = tid >> 6, lane = tid & 63;
  const int quad = lane >> 4, l15 = lane & 15;
  const int wm = wave >> 1, wn = wave & 1;

  // ---- XCD-pinned decode ----
  int bx = blockIdx.x;
  int task, xt, yt, b;
  if (bx < 432) {                       // V: chunk v = x + 9*b, slot = v%8, inner = y(6)
    int slot = bx & 7, rest = bx >> 3;
    int y = rest % 6, vhi = rest / 6;
    int v = slot + 8 * vhi;
    task = 2; xt = v % 9; b = v / 9; yt = y;
  } else if (bx < 816) {                // Q: chunk q = y + 8*b, slot = q%8, inner = x(6)
    int t = bx - 432;
    int slot = t & 7, rest = t >> 3;
    int x = rest % 6, qhi = rest / 6;
    int q = slot + 8 * qhi;
    task = 0; xt = x; yt = q & 7; b = q >> 3;
  } else {                              // K: chunk k = y + 9*b, slot = k%8, inner = x(6)
    int t = bx - 816;
    int slot = t & 7, rest = t >> 3;
    int x = rest % 6, khi = rest / 6;
    int k = slot + 8 * khi;
    task = 1; xt = x; yt = k % 9; b = k / 9;
  }
  const int rowTile = yt * 128, colTile = xt * 128;
  const ushort_t* Xb = Xm + (size_t)b * LPAD * DMODEL;
  const ushort_t* A = task == 2 ? Wvb : Xb;
  const ushort_t* W = task == 2 ? Xb : (task == 0 ? Wqb : Wkb);
  const float* bias = task == 2 ? bv : (task == 0 ? bq : bk);

  const int srow = tid >> 2;          // 0..63
  const int scol = (tid & 3) << 3;    // 0,8,16,24

  f32x4 acc[4][4] = {};

  for (int k0 = 0; k0 < DMODEL; k0 += 64) {
#pragma unroll
    for (int kk = 0; kk < 2; ++kk)
#pragma unroll
      for (int is = 0; is < 2; ++is) {
        int r = is * 64 + srow;
        int lb = kk * 4096 + is * 2048 + wave * 512;
        stage16(A + (size_t)(rowTile + r) * DMODEL + k0 + kk * 32 + scol, As + lb);
        stage16(W + (size_t)(colTile + r) * DMODEL + k0 + kk * 32 + scol, Bs + lb);
      }
    __syncthreads();
#pragma unroll
    for (int kk = 0; kk < 2; ++kk) {
      bf16x8 af[4], bfr[4];
#pragma unroll
      for (int mt = 0; mt < 4; ++mt)
        af[mt] = *(const bf16x8*)&As[kk * 4096 + (wm * 64 + mt * 16 + l15) * 32 + quad * 8];
#pragma unroll
      for (int nt = 0; nt < 4; ++nt)
        bfr[nt] = *(const bf16x8*)&Bs[kk * 4096 + (wn * 64 + nt * 16 + l15) * 32 + quad * 8];
#pragma unroll
      for (int mt = 0; mt < 4; ++mt)
#pragma unroll
        for (int nt = 0; nt < 4; ++nt)
          acc[mt][nt] = __builtin_amdgcn_mfma_f32_16x16x32_bf16(af[mt], bfr[nt], acc[mt][nt], 0, 0, 0);
    }
    __syncthreads();
  }

  if (task == 2) {
    // C[row=d][col=l] -> V^T, coalesced along l
#pragma unroll
    for (int mt = 0; mt < 4; ++mt) {
      int row0 = rowTile + wm * 64 + mt * 16 + quad * 4;
      float bvr[4];
#pragma unroll
      for (int r = 0; r < 4; ++r) bvr[r] = bias[row0 + r];
#pragma unroll
      for (int nt = 0; nt < 4; ++nt) {
        int col = colTile + wn * 64 + nt * 16 + l15;
#pragma unroll
        for (int r = 0; r < 4; ++r) {
          int row = row0 + r;
          Vtb[(((size_t)b * NH + (row >> 6)) * DH + (row & 63)) * LPAD + col] =
              f2b(acc[mt][nt][r] + bvr[r]);
        }
      }
    }
  } else {
    ushort_t* out = task == 0 ? Qb : Kb;
    const int Rows = task == 0 ? SEQ : LPAD;
    const float scale = task == 0 ? CEXP : 1.0f;
#pragma unroll
    for (int mt = 0; mt < 4; ++mt)
#pragma unroll
      for (int nt = 0; nt < 4; ++nt) {
        int row0 = rowTile + wm * 64 + mt * 16 + quad * 4;
        int col = colTile + wn * 64 + nt * 16 + l15;
        int h = col >> 6, d = col & 63;
        float bsv = bias[col];
#pragma unroll
        for (int r = 0; r < 4; ++r)
          out[(((size_t)b * NH + h) * Rows + (row0 + r)) * DH + d] =
              f2b((acc[mt][nt][r] + bsv) * scale);
      }
  }
}

// Attention: 128-key tiles (9 iters), no-rescale softmax, l via ones-MFMA.
// Grid (96 bh, 8 qt): all q-tiles of a (b,h) share an XCD -> K/V L2-resident.
// Block = 128 q rows, 4 waves x 32 rows. Q pre-scaled so p = exp2(s).
__global__ __launch_bounds__(256, 3) void attn(const ushort_t* __restrict__ Q,
                                               const ushort_t* __restrict__ K,
                                               const ushort_t* __restrict__ Vt,
                                               float* __restrict__ Out) {
  __shared__ __align__(16) ushort_t Ks[2 * 4096];   // [kk d-half][key128][32]
  __shared__ __align__(16) ushort_t Vs[4 * 2048];   // [kc key-32][d64][32]
  __shared__ __align__(16) ushort_t Ps[4 * 2304];   // per wave: 32 rows * stride 72

  const int tid = threadIdx.x, wave = tid >> 6, lane = tid & 63;
  const int quad = lane >> 4, l15 = lane & 15;
  const int bh = blockIdx.x, qt = blockIdx.y;
  const int h = bh % NH, b = bh / NH;

  const ushort_t* Qp = Q + (((size_t)b * NH + h) * SEQ + qt * 128) * DH;
  const ushort_t* Kp = K + ((size_t)b * NH + h) * LPAD * DH;
  const ushort_t* Vp = Vt + ((size_t)b * NH + h) * DH * LPAD;
  ushort_t* Pw = Ps + wave * 2304;

  bf16x8 qf[2][2];
#pragma unroll
  for (int mt = 0; mt < 2; ++mt)
#pragma unroll
    for (int kk = 0; kk < 2; ++kk)
      qf[mt][kk] = *(const bf16x8*)&Qp[(wave * 32 + mt * 16 + l15) * DH + kk * 32 + quad * 8];

  // ones fragment for the l (denominator) MFMA
  bf16x8 ones8;
#pragma unroll
  for (int j = 0; j < 8; ++j) ones8[j] = (short)0x3f80;

  f32x4 ob[2][4] = {};
  f32x4 obl[2] = {};

  const int srow = tid >> 2;          // 0..63
  const int scol = (tid & 3) << 3;    // 0,8,16,24

  for (int kt = 0; kt < 9; ++kt) {
    const int key0 = kt * 128;
#pragma unroll
    for (int kk = 0; kk < 2; ++kk)
#pragma unroll
      for (int is = 0; is < 2; ++is) {
        int krow = is * 64 + srow;
        stage16(Kp + (size_t)(key0 + krow) * DH + kk * 32 + scol,
                Ks + kk * 4096 + is * 2048 + wave * 512);
      }
#pragma unroll
    for (int kc = 0; kc < 4; ++kc)
      stage16(Vp + (size_t)srow * LPAD + key0 + kc * 32 + scol,
              Vs + kc * 2048 + wave * 512);
    __syncthreads();

#pragma unroll
    for (int half = 0; half < 2; ++half) {
      // S = Q K^T for 32 q rows x 64 keys
      f32x4 sc[2][4] = {};
#pragma unroll
      for (int kk = 0; kk < 2; ++kk)
#pragma unroll
        for (int nt = 0; nt < 4; ++nt) {
          bf16x8 kf = *(const bf16x8*)&Ks[kk * 4096 + (half * 64 + nt * 16 + l15) * 32 + quad * 8];
#pragma unroll
          for (int mt = 0; mt < 2; ++mt)
            sc[mt][nt] = __builtin_amdgcn_mfma_f32_16x16x32_bf16(qf[mt][kk], kf, sc[mt][nt], 0, 0, 0);
        }

      // P = exp2(S) truncated to bf16 (denominator uses the same truncated P via MFMA)
      if (kt < 8) {
#pragma unroll
        for (int mt = 0; mt < 2; ++mt)
#pragma unroll
          for (int nt = 0; nt < 4; ++nt)
#pragma unroll
            for (int r = 0; r < 4; ++r) {
              union { float f; unsigned u; } cu;
              cu.f = EXP2F(sc[mt][nt][r]);
              Pw[(mt * 16 + quad * 4 + r) * 72 + nt * 16 + l15] = (ushort_t)(cu.u >> 16);
            }
      } else {
#pragma unroll
        for (int mt = 0; mt < 2; ++mt)
#pragma unroll
          for (int nt = 0; nt < 4; ++nt) {
            int key = key0 + half * 64 + nt * 16 + l15;
            bool valid = key < LREAL;
#pragma unroll
            for (int r = 0; r < 4; ++r) {
              union { float f; unsigned u; } cu;
              cu.f = valid ? EXP2F(sc[mt][nt][r]) : 0.f;
              Pw[(mt * 16 + quad * 4 + r) * 72 + nt * 16 + l15] = (ushort_t)(cu.u >> 16);
            }
          }
      }

      // O += P V ; l += P 1
#pragma unroll
      for (int kc2 = 0; kc2 < 2; ++kc2) {
        int kcg = half * 2 + kc2;
        bf16x8 pf[2];
#pragma unroll
        for (int mt = 0; mt < 2; ++mt)
          pf[mt] = *(const bf16x8*)&Pw[(mt * 16 + l15) * 72 + kc2 * 32 + quad * 8];
#pragma unroll
        for (int dt = 0; dt < 4; ++dt) {
          bf16x8 vf = *(const bf16x8*)&Vs[kcg * 2048 + (dt * 16 + l15) * 32 + quad * 8];
#pragma unroll
          for (int mt = 0; mt < 2; ++mt)
            ob[mt][dt] = __builtin_amdgcn_mfma_f32_16x16x32_bf16(pf[mt], vf, ob[mt][dt], 0, 0, 0);
        }
#pragma unroll
        for (int mt = 0; mt < 2; ++mt)
          obl[mt] = __builtin_amdgcn_mfma_f32_16x16x32_bf16(pf[mt], ones8, obl[mt], 0, 0, 0);
      }
    }
    __syncthreads();
  }

#pragma unroll
  for (int mt = 0; mt < 2; ++mt) {
    int row0 = qt * 128 + wave * 32 + mt * 16 + quad * 4;
    f32x4 linv;
#pragma unroll
    for (int r = 0; r < 4; ++r) linv[r] = 1.0f / obl[mt][r];
#pragma unroll
    for (int dt = 0; dt < 4; ++dt) {
      int col = h * DH + dt * 16 + l15;
#pragma unroll
      for (int r = 0; r < 4; ++r)
        Out[((size_t)b * SEQ + row0 + r) * DMODEL + col] = ob[mt][dt][r] * linv[r];
    }
  }
}

extern "C" void kernel_launch(void* const* d_in, const int* in_sizes, int n_in,
                              void* d_out, int out_size, void* d_ws, size_t ws_size,
                              hipStream_t stream) {
  const float* hidden = (const float*)d_in[0];
  const float* memv   = (const float*)d_in[1];
  const float* Wq = (const float*)d_in[2];
  const float* bq = (const float*)d_in[3];
  const float* Wk = (const float*)d_in[4];
  const float* bk = (const float*)d_in[5];
  const float* Wv = (const float*)d_in[6];
  const float* bv = (const float*)d_in[7];
  float* out = (float*)d_out;

  char* ws = (char*)d_ws;
  size_t off = 0;
  ushort_t* Xm  = (ushort_t*)(ws + off); off += (size_t)BATCH * LPAD * DMODEL * 2;
  ushort_t* Wqb = (ushort_t*)(ws + off); off += (size_t)DMODEL * DMODEL * 2;
  ushort_t* Wkb = (ushort_t*)(ws + off); off += (size_t)DMODEL * DMODEL * 2;
  ushort_t* Wvb = (ushort_t*)(ws + off); off += (size_t)DMODEL * DMODEL * 2;
  ushort_t* Qb  = (ushort_t*)(ws + off); off += (size_t)BATCH * NH * SEQ * DH * 2;
  ushort_t* Kb  = (ushort_t*)(ws + off); off += (size_t)BATCH * NH * LPAD * DH * 2;
  ushort_t* Vtb = (ushort_t*)(ws + off);

  prep<<<dim3(8640), 256, 0, stream>>>(hidden, memv, Wq, Wk, Wv, Xm, Wqb, Wkb, Wvb);
  gemm_fused<<<dim3(1248), 256, 0, stream>>>(Xm, Wqb, Wkb, Wvb, bq, bk, bv, Qb, Kb, Vtb);
  attn<<<dim3(96, 8), 256, 0, stream>>>(Qb, Kb, Vtb, out);
}

// Round 4
// 185.595 us; speedup vs baseline: 1.4021x; 1.0029x over previous
//
#include <hip/hip_runtime.h>

typedef unsigned short ushort_t;
typedef __attribute__((ext_vector_type(8))) short bf16x8;
typedef __attribute__((ext_vector_type(4))) short s16x4;
typedef __attribute__((ext_vector_type(4))) float f32x4;

#define BATCH 8
#define SEQ   1024
#define MEMT  8
#define LREAL 1032
#define LPAD  1152   // 9 * 128
#define DMODEL 768
#define NH    12
#define DH    64

// 0.125 * log2(e): Q is pre-scaled by this in the GEMM epilogue, so attn does exp2(s) directly.
#define CEXP 0.18033688011112042f

// round-to-nearest-even fp32 -> bf16 (raw ushort bits)
__device__ __forceinline__ ushort_t f2b(float x) {
  union { float f; unsigned u; } c; c.f = x;
  unsigned u = c.u;
  unsigned r = (u + 0x7fffu + ((u >> 16) & 1u)) >> 16;
  return (ushort_t)r;
}

#if defined(__has_builtin)
#if __has_builtin(__builtin_amdgcn_global_load_lds)
#define HAVE_GLL 1
#endif
#if __has_builtin(__builtin_amdgcn_exp2f)
#define EXP2F(x) __builtin_amdgcn_exp2f(x)
#endif
#endif
#ifndef EXP2F
#define EXP2F(x) __expf((x) * 0.6931471805599453f)
#endif

// Stage 16 bytes/lane: global (per-lane addr) -> LDS (wave-uniform base, HW adds lane*16)
__device__ __forceinline__ void stage16(const ushort_t* g, ushort_t* lds_wave_base) {
#ifdef HAVE_GLL
  __builtin_amdgcn_global_load_lds(
      (const __attribute__((address_space(1))) unsigned int*)g,
      (__attribute__((address_space(3))) unsigned int*)lds_wave_base,
      16, 0, 0);
#else
  int lane = threadIdx.x & 63;
  *(bf16x8*)(lds_wave_base + lane * 8) = *(const bf16x8*)g;
#endif
}

// Merged prep: blocks [0,6912) build Xm (bf16, memory appended, zero-pad to LPAD rows);
// blocks [6912,8640) cast the 3 weight matrices.
__global__ __launch_bounds__(256) void prep(const float* __restrict__ hidden,
                                            const float* __restrict__ memv,
                                            const float* __restrict__ Wq,
                                            const float* __restrict__ Wk,
                                            const float* __restrict__ Wv,
                                            ushort_t* __restrict__ Xm,
                                            ushort_t* __restrict__ Wqb,
                                            ushort_t* __restrict__ Wkb,
                                            ushort_t* __restrict__ Wvb) {
  int bx = blockIdx.x;
  if (bx < 6912) {
    size_t idx = ((size_t)bx * 256 + threadIdx.x) * 4;
    const size_t perB = (size_t)LPAD * DMODEL;
    int b = (int)(idx / perB);
    size_t rem = idx - (size_t)b * perB;
    int row = (int)(rem / DMODEL);
    int col = (int)(rem - (size_t)row * DMODEL);
    f32x4 v;
    if (row < SEQ) {
      v = *(const f32x4*)(hidden + ((size_t)b * SEQ + row) * DMODEL + col);
    } else if (row < LREAL) {
      v = *(const f32x4*)(memv + (size_t)(row - SEQ) * DMODEL + col);
    } else {
      v = (f32x4){0.f, 0.f, 0.f, 0.f};
    }
    s16x4 p;
    p[0] = (short)f2b(v[0]); p[1] = (short)f2b(v[1]);
    p[2] = (short)f2b(v[2]); p[3] = (short)f2b(v[3]);
    *(s16x4*)(Xm + idx) = p;
  } else {
    int t = bx - 6912;            // 1728 blocks, 576 per matrix
    int m = t / 576;
    int i = (t - m * 576) * 256 + threadIdx.x;
    const float* src = m == 0 ? Wq : (m == 1 ? Wk : Wv);
    ushort_t* dst = m == 0 ? Wqb : (m == 1 ? Wkb : Wvb);
    f32x4 v = *(const f32x4*)(src + (size_t)i * 4);
    s16x4 p;
    p[0] = (short)f2b(v[0]); p[1] = (short)f2b(v[1]);
    p[2] = (short)f2b(v[2]); p[3] = (short)f2b(v[3]);
    *(s16x4*)(dst + (size_t)i * 4) = p;
  }
}

// Fused QKV projection, BK=64, XCD-pinned 1D grid of 1248 blocks x 512 threads.
// 8 waves in 2x4 over a 128x128 tile (per-wave 64x32 -> 32 AGPR, high occupancy).
// Coalesced epilogue: acc -> bf16 LDS image (stride 136) -> dwordx4 stores.
__global__ __launch_bounds__(512, 4) void gemm_fused(
    const ushort_t* __restrict__ Xm,
    const ushort_t* __restrict__ Wqb, const ushort_t* __restrict__ Wkb,
    const ushort_t* __restrict__ Wvb,
    const float* __restrict__ bq, const float* __restrict__ bk,
    const float* __restrict__ bv,
    ushort_t* __restrict__ Qb, ushort_t* __restrict__ Kb,
    ushort_t* __restrict__ Vtb) {
  // staging: As = S[0..8192), Bs = S[8192..16384); epilogue image: S[0..17408), stride 136
  __shared__ __align__(16) ushort_t S[17408];
  ushort_t* As = S;
  ushort_t* Bs = S + 8192;

  const int tid = threadIdx.x;
  const int wave = tid >> 6, lane = tid & 63;
  const int quad = lane >> 4, l15 = lane & 15;
  const int wm = wave >> 2, wn = wave & 3;

  // ---- XCD-pinned decode (same as round 3) ----
  int bx = blockIdx.x;
  int task, xt, yt, b;
  if (bx < 432) {
    int slot = bx & 7, rest = bx >> 3;
    int y = rest % 6, vhi = rest / 6;
    int v = slot + 8 * vhi;
    task = 2; xt = v % 9; b = v / 9; yt = y;
  } else if (bx < 816) {
    int t = bx - 432;
    int slot = t & 7, rest = t >> 3;
    int x = rest % 6, qhi = rest / 6;
    int q = slot + 8 * qhi;
    task = 0; xt = x; yt = q & 7; b = q >> 3;
  } else {
    int t = bx - 816;
    int slot = t & 7, rest = t >> 3;
    int x = rest % 6, khi = rest / 6;
    int k = slot + 8 * khi;
    task = 1; xt = x; yt = k % 9; b = k / 9;
  }
  const int rowTile = yt * 128, colTile = xt * 128;
  const ushort_t* Xb = Xm + (size_t)b * LPAD * DMODEL;
  const ushort_t* A = task == 2 ? Wvb : Xb;
  const ushort_t* W = task == 2 ? Xb : (task == 0 ? Wqb : Wkb);
  const float* bias = task == 2 ? bv : (task == 0 ? bq : bk);

  // staging decomposition: 32 wave-units/iter (16 As + 16 Bs), 4 per wave.
  // unit u: matrix = u>=16, x = u&15, kk = x>>3, rg = x&7.
  // global row = rowTile/colTile + rg*16 + lane>>2 ; col = k0 + kk*32 + (lane&3)*8
  const int lrow4 = lane >> 2, lcol8 = (lane & 3) << 3;

  f32x4 acc[4][2] = {};

  for (int k0 = 0; k0 < DMODEL; k0 += 64) {
#pragma unroll
    for (int s = 0; s < 4; ++s) {
      int u = wave * 4 + s;
      int x = u & 15;
      int kk = x >> 3, rg = x & 7;
      int lb = kk * 4096 + rg * 512;
      if (u < 16) {
        stage16(A + (size_t)(rowTile + rg * 16 + lrow4) * DMODEL + k0 + kk * 32 + lcol8,
                As + lb);
      } else {
        stage16(W + (size_t)(colTile + rg * 16 + lrow4) * DMODEL + k0 + kk * 32 + lcol8,
                Bs + lb);
      }
    }
    __syncthreads();
#pragma unroll
    for (int kk = 0; kk < 2; ++kk) {
      bf16x8 af[4], bfr[2];
#pragma unroll
      for (int mt = 0; mt < 4; ++mt)
        af[mt] = *(const bf16x8*)&As[kk * 4096 + (wm * 64 + mt * 16 + l15) * 32 + quad * 8];
#pragma unroll
      for (int nt = 0; nt < 2; ++nt)
        bfr[nt] = *(const bf16x8*)&Bs[kk * 4096 + (wn * 32 + nt * 16 + l15) * 32 + quad * 8];
#pragma unroll
      for (int mt = 0; mt < 4; ++mt)
#pragma unroll
        for (int nt = 0; nt < 2; ++nt)
          acc[mt][nt] = __builtin_amdgcn_mfma_f32_16x16x32_bf16(af[mt], bfr[nt], acc[mt][nt], 0, 0, 0);
    }
    __syncthreads();
  }

  // ---- epilogue: acc -> LDS bf16 image (stride 136), then coalesced stores ----
  const float scale = task == 0 ? CEXP : 1.0f;
#pragma unroll
  for (int mt = 0; mt < 4; ++mt)
#pragma unroll
    for (int nt = 0; nt < 2; ++nt) {
      int lr0 = wm * 64 + mt * 16 + quad * 4;
      int lc = wn * 32 + nt * 16 + l15;
#pragma unroll
      for (int r = 0; r < 4; ++r) {
        float bsv = (task == 2) ? bias[rowTile + lr0 + r] : bias[colTile + lc];
        S[(lr0 + r) * 136 + lc] = f2b((acc[mt][nt][r] + bsv) * scale);
      }
    }
  __syncthreads();

  {
    int row = tid >> 2;               // 0..127 tile row
    int segu = (tid & 3) * 32;        // ushort offset in tile row
    bf16x8 v0 = *(const bf16x8*)&S[row * 136 + segu + 0];
    bf16x8 v1 = *(const bf16x8*)&S[row * 136 + segu + 8];
    bf16x8 v2 = *(const bf16x8*)&S[row * 136 + segu + 16];
    bf16x8 v3 = *(const bf16x8*)&S[row * 136 + segu + 24];
    if (task == 2) {
      int d = rowTile + row;          // global d row
      ushort_t* gp = Vtb + (((size_t)b * NH + (d >> 6)) * DH + (d & 63)) * LPAD + colTile + segu;
      *(bf16x8*)(gp + 0) = v0;  *(bf16x8*)(gp + 8) = v1;
      *(bf16x8*)(gp + 16) = v2; *(bf16x8*)(gp + 24) = v3;
    } else {
      ushort_t* out = task == 0 ? Qb : Kb;
      const int Rows = task == 0 ? SEQ : LPAD;
      int colbase = colTile + segu;   // 32-wide segment stays within one head
      int h = colbase >> 6, dd = colbase & 63;
      ushort_t* gp = out + (((size_t)b * NH + h) * Rows + rowTile + row) * DH + dd;
      *(bf16x8*)(gp + 0) = v0;  *(bf16x8*)(gp + 8) = v1;
      *(bf16x8*)(gp + 16) = v2; *(bf16x8*)(gp + 24) = v3;
    }
  }
}

// Attention: 128-key tiles (9 iters), no-rescale softmax, l via ones-MFMA.
// Grid (96 bh, 8 qt): all q-tiles of a (b,h) share an XCD -> K/V L2-resident.
// Block = 128 q rows, 4 waves x 32 rows. Q pre-scaled so p = exp2(s).
__global__ __launch_bounds__(256, 3) void attn(const ushort_t* __restrict__ Q,
                                               const ushort_t* __restrict__ K,
                                               const ushort_t* __restrict__ Vt,
                                               float* __restrict__ Out) {
  __shared__ __align__(16) ushort_t Ks[2 * 4096];   // [kk d-half][key128][32]
  __shared__ __align__(16) ushort_t Vs[4 * 2048];   // [kc key-32][d64][32]
  __shared__ __align__(16) ushort_t Ps[4 * 2304];   // per wave: 32 rows * stride 72

  const int tid = threadIdx.x, wave = tid >> 6, lane = tid & 63;
  const int quad = lane >> 4, l15 = lane & 15;
  const int bh = blockIdx.x, qt = blockIdx.y;
  const int h = bh % NH, b = bh / NH;

  const ushort_t* Qp = Q + (((size_t)b * NH + h) * SEQ + qt * 128) * DH;
  const ushort_t* Kp = K + ((size_t)b * NH + h) * LPAD * DH;
  const ushort_t* Vp = Vt + ((size_t)b * NH + h) * DH * LPAD;
  ushort_t* Pw = Ps + wave * 2304;

  bf16x8 qf[2][2];
#pragma unroll
  for (int mt = 0; mt < 2; ++mt)
#pragma unroll
    for (int kk = 0; kk < 2; ++kk)
      qf[mt][kk] = *(const bf16x8*)&Qp[(wave * 32 + mt * 16 + l15) * DH + kk * 32 + quad * 8];

  bf16x8 ones8;
#pragma unroll
  for (int j = 0; j < 8; ++j) ones8[j] = (short)0x3f80;

  f32x4 ob[2][4] = {};
  f32x4 obl[2] = {};

  const int srow = tid >> 2;          // 0..63
  const int scol = (tid & 3) << 3;    // 0,8,16,24

  for (int kt = 0; kt < 9; ++kt) {
    const int key0 = kt * 128;
#pragma unroll
    for (int kk = 0; kk < 2; ++kk)
#pragma unroll
      for (int is = 0; is < 2; ++is) {
        int krow = is * 64 + srow;
        stage16(Kp + (size_t)(key0 + krow) * DH + kk * 32 + scol,
                Ks + kk * 4096 + is * 2048 + wave * 512);
      }
#pragma unroll
    for (int kc = 0; kc < 4; ++kc)
      stage16(Vp + (size_t)srow * LPAD + key0 + kc * 32 + scol,
              Vs + kc * 2048 + wave * 512);
    __syncthreads();

#pragma unroll
    for (int half = 0; half < 2; ++half) {
      f32x4 sc[2][4] = {};
#pragma unroll
      for (int kk = 0; kk < 2; ++kk)
#pragma unroll
        for (int nt = 0; nt < 4; ++nt) {
          bf16x8 kf = *(const bf16x8*)&Ks[kk * 4096 + (half * 64 + nt * 16 + l15) * 32 + quad * 8];
#pragma unroll
          for (int mt = 0; mt < 2; ++mt)
            sc[mt][nt] = __builtin_amdgcn_mfma_f32_16x16x32_bf16(qf[mt][kk], kf, sc[mt][nt], 0, 0, 0);
        }

      if (kt < 8) {
#pragma unroll
        for (int mt = 0; mt < 2; ++mt)
#pragma unroll
          for (int nt = 0; nt < 4; ++nt)
#pragma unroll
            for (int r = 0; r < 4; ++r) {
              union { float f; unsigned u; } cu;
              cu.f = EXP2F(sc[mt][nt][r]);
              Pw[(mt * 16 + quad * 4 + r) * 72 + nt * 16 + l15] = (ushort_t)(cu.u >> 16);
            }
      } else {
#pragma unroll
        for (int mt = 0; mt < 2; ++mt)
#pragma unroll
          for (int nt = 0; nt < 4; ++nt) {
            int key = key0 + half * 64 + nt * 16 + l15;
            bool valid = key < LREAL;
#pragma unroll
            for (int r = 0; r < 4; ++r) {
              union { float f; unsigned u; } cu;
              cu.f = valid ? EXP2F(sc[mt][nt][r]) : 0.f;
              Pw[(mt * 16 + quad * 4 + r) * 72 + nt * 16 + l15] = (ushort_t)(cu.u >> 16);
            }
          }
      }

#pragma unroll
      for (int kc2 = 0; kc2 < 2; ++kc2) {
        int kcg = half * 2 + kc2;
        bf16x8 pf[2];
#pragma unroll
        for (int mt = 0; mt < 2; ++mt)
          pf[mt] = *(const bf16x8*)&Pw[(mt * 16 + l15) * 72 + kc2 * 32 + quad * 8];
#pragma unroll
        for (int dt = 0; dt < 4; ++dt) {
          bf16x8 vf = *(const bf16x8*)&Vs[kcg * 2048 + (dt * 16 + l15) * 32 + quad * 8];
#pragma unroll
          for (int mt = 0; mt < 2; ++mt)
            ob[mt][dt] = __builtin_amdgcn_mfma_f32_16x16x32_bf16(pf[mt], vf, ob[mt][dt], 0, 0, 0);
        }
#pragma unroll
        for (int mt = 0; mt < 2; ++mt)
          obl[mt] = __builtin_amdgcn_mfma_f32_16x16x32_bf16(pf[mt], ones8, obl[mt], 0, 0, 0);
      }
    }
    __syncthreads();
  }

#pragma unroll
  for (int mt = 0; mt < 2; ++mt) {
    int row0 = qt * 128 + wave * 32 + mt * 16 + quad * 4;
    f32x4 linv;
#pragma unroll
    for (int r = 0; r < 4; ++r) linv[r] = 1.0f / obl[mt][r];
#pragma unroll
    for (int dt = 0; dt < 4; ++dt) {
      int col = h * DH + dt * 16 + l15;
#pragma unroll
      for (int r = 0; r < 4; ++r)
        Out[((size_t)b * SEQ + row0 + r) * DMODEL + col] = ob[mt][dt][r] * linv[r];
    }
  }
}

extern "C" void kernel_launch(void* const* d_in, const int* in_sizes, int n_in,
                              void* d_out, int out_size, void* d_ws, size_t ws_size,
                              hipStream_t stream) {
  const float* hidden = (const float*)d_in[0];
  const float* memv   = (const float*)d_in[1];
  const float* Wq = (const float*)d_in[2];
  const float* bq = (const float*)d_in[3];
  const float* Wk = (const float*)d_in[4];
  const float* bk = (const float*)d_in[5];
  const float* Wv = (const float*)d_in[6];
  const float* bv = (const float*)d_in[7];
  float* out = (float*)d_out;

  char* ws = (char*)d_ws;
  size_t off = 0;
  ushort_t* Xm  = (ushort_t*)(ws + off); off += (size_t)BATCH * LPAD * DMODEL * 2;
  ushort_t* Wqb = (ushort_t*)(ws + off); off += (size_t)DMODEL * DMODEL * 2;
  ushort_t* Wkb = (ushort_t*)(ws + off); off += (size_t)DMODEL * DMODEL * 2;
  ushort_t* Wvb = (ushort_t*)(ws + off); off += (size_t)DMODEL * DMODEL * 2;
  ushort_t* Qb  = (ushort_t*)(ws + off); off += (size_t)BATCH * NH * SEQ * DH * 2;
  ushort_t* Kb  = (ushort_t*)(ws + off); off += (size_t)BATCH * NH * LPAD * DH * 2;
  ushort_t* Vtb = (ushort_t*)(ws + off);

  prep<<<dim3(8640), 256, 0, stream>>>(hidden, memv, Wq, Wk, Wv, Xm, Wqb, Wkb, Wvb);
  gemm_fused<<<dim3(1248), 512, 0, stream>>>(Xm, Wqb, Wkb, Wvb, bq, bk, bv, Qb, Kb, Vtb);
  attn<<<dim3(96, 8), 256, 0, stream>>>(Qb, Kb, Vtb, out);
}

// Round 5
// 181.670 us; speedup vs baseline: 1.4324x; 1.0216x over previous
//
#include <hip/hip_runtime.h>

typedef unsigned short ushort_t;
typedef __attribute__((ext_vector_type(8))) short bf16x8;
typedef __attribute__((ext_vector_type(4))) short s16x4;
typedef __attribute__((ext_vector_type(4))) float f32x4;

#define BATCH 8
#define SEQ   1024
#define MEMT  8
#define LREAL 1032
#define LPAD  1152   // 9 * 128
#define DMODEL 768
#define NH    12
#define DH    64

// 0.125 * log2(e): Q pre-scaled in GEMM epilogue so attn does exp2(s) directly.
#define CEXP 0.18033688011112042f

__device__ __forceinline__ ushort_t f2b(float x) {
  union { float f; unsigned u; } c; c.f = x;
  unsigned u = c.u;
  unsigned r = (u + 0x7fffu + ((u >> 16) & 1u)) >> 16;
  return (ushort_t)r;
}

#if defined(__has_builtin)
#if __has_builtin(__builtin_amdgcn_global_load_lds)
#define HAVE_GLL 1
#endif
#if __has_builtin(__builtin_amdgcn_exp2f)
#define EXP2F(x) __builtin_amdgcn_exp2f(x)
#endif
#endif
#ifndef EXP2F
#define EXP2F(x) __expf((x) * 0.6931471805599453f)
#endif

__device__ __forceinline__ void stage16(const ushort_t* g, ushort_t* lds_wave_base) {
#ifdef HAVE_GLL
  __builtin_amdgcn_global_load_lds(
      (const __attribute__((address_space(1))) unsigned int*)g,
      (__attribute__((address_space(3))) unsigned int*)lds_wave_base,
      16, 0, 0);
#else
  int lane = threadIdx.x & 63;
  *(bf16x8*)(lds_wave_base + lane * 8) = *(const bf16x8*)g;
#endif
}

// Merged prep (32-bit indexing): blocks [0,6912) build Xm; [6912,8640) cast weights.
__global__ __launch_bounds__(256) void prep(const float* __restrict__ hidden,
                                            const float* __restrict__ memv,
                                            const float* __restrict__ Wq,
                                            const float* __restrict__ Wk,
                                            const float* __restrict__ Wv,
                                            ushort_t* __restrict__ Xm,
                                            ushort_t* __restrict__ Wqb,
                                            ushort_t* __restrict__ Wkb,
                                            ushort_t* __restrict__ Wvb) {
  int bx = blockIdx.x;
  if (bx < 6912) {
    unsigned idx = ((unsigned)bx * 256u + threadIdx.x) * 4u;
    const unsigned perB = (unsigned)LPAD * DMODEL;
    unsigned b = idx / perB;
    unsigned rem = idx - b * perB;
    unsigned row = rem / DMODEL;
    unsigned col = rem - row * DMODEL;
    f32x4 v;
    if (row < SEQ) {
      v = *(const f32x4*)(hidden + ((size_t)b * SEQ + row) * DMODEL + col);
    } else if (row < LREAL) {
      v = *(const f32x4*)(memv + (size_t)(row - SEQ) * DMODEL + col);
    } else {
      v = (f32x4){0.f, 0.f, 0.f, 0.f};
    }
    s16x4 p;
    p[0] = (short)f2b(v[0]); p[1] = (short)f2b(v[1]);
    p[2] = (short)f2b(v[2]); p[3] = (short)f2b(v[3]);
    *(s16x4*)(Xm + idx) = p;
  } else {
    int t = bx - 6912;
    int m = t / 576;
    int i = (t - m * 576) * 256 + threadIdx.x;
    const float* src = m == 0 ? Wq : (m == 1 ? Wk : Wv);
    ushort_t* dst = m == 0 ? Wqb : (m == 1 ? Wkb : Wvb);
    f32x4 v = *(const f32x4*)(src + (size_t)i * 4);
    s16x4 p;
    p[0] = (short)f2b(v[0]); p[1] = (short)f2b(v[1]);
    p[2] = (short)f2b(v[2]); p[3] = (short)f2b(v[3]);
    *(s16x4*)(dst + (size_t)i * 4) = p;
  }
}

// Fused QKV projection: single-barrier prefetch pipeline, BK=32 double-buffered.
// Staging dbuf (2 x 16 KB) lives inside the 34.8 KB epilogue image -> LDS unchanged.
// 512 threads, 8 waves 2x4 over 128x128 tile. XCD-pinned 1D grid of 1248 blocks.
__global__ __launch_bounds__(512, 4) void gemm_fused(
    const ushort_t* __restrict__ Xm,
    const ushort_t* __restrict__ Wqb, const ushort_t* __restrict__ Wkb,
    const ushort_t* __restrict__ Wvb,
    const float* __restrict__ bq, const float* __restrict__ bk,
    const float* __restrict__ bv,
    ushort_t* __restrict__ Qb, ushort_t* __restrict__ Kb,
    ushort_t* __restrict__ Vtb) {
  // buf i at S + i*8192: As @ +0 (128x32), Bs @ +4096. Epilogue image: 128 x 136.
  __shared__ __align__(16) ushort_t S[17408];

  const int tid = threadIdx.x;
  const int wave = tid >> 6, lane = tid & 63;
  const int quad = lane >> 4, l15 = lane & 15;
  const int wm = wave >> 2, wn = wave & 3;
  const int lrow4 = lane >> 2, lcol8 = (lane & 3) << 3;

  // ---- XCD-pinned decode ----
  int bx = blockIdx.x;
  int task, xt, yt, b;
  if (bx < 432) {
    int slot = bx & 7, rest = bx >> 3;
    int y = rest % 6, vhi = rest / 6;
    int v = slot + 8 * vhi;
    task = 2; xt = v % 9; b = v / 9; yt = y;
  } else if (bx < 816) {
    int t = bx - 432;
    int slot = t & 7, rest = t >> 3;
    int x = rest % 6, qhi = rest / 6;
    int q = slot + 8 * qhi;
    task = 0; xt = x; yt = q & 7; b = q >> 3;
  } else {
    int t = bx - 816;
    int slot = t & 7, rest = t >> 3;
    int x = rest % 6, khi = rest / 6;
    int k = slot + 8 * khi;
    task = 1; xt = x; yt = k % 9; b = k / 9;
  }
  const int rowTile = yt * 128, colTile = xt * 128;
  const ushort_t* Xb = Xm + (size_t)b * LPAD * DMODEL;
  const ushort_t* A = task == 2 ? Wvb : Xb;
  const ushort_t* W = task == 2 ? Xb : (task == 0 ? Wqb : Wkb);
  const float* bias = task == 2 ? bv : (task == 0 ? bq : bk);

  // per-iter staging: wave w stages As chunk w (rows w*16..+15) and Bs chunk w.
  const ushort_t* Arow = A + (size_t)(rowTile + wave * 16 + lrow4) * DMODEL + lcol8;
  const ushort_t* Wrow = W + (size_t)(colTile + wave * 16 + lrow4) * DMODEL + lcol8;

  f32x4 acc[4][2] = {};

  // prologue: stage tile 0 into buf0
  stage16(Arow, S + wave * 512);
  stage16(Wrow, S + 4096 + wave * 512);
  __syncthreads();

  for (int i = 0; i < 24; ++i) {
    ushort_t* cur = S + ((i & 1) << 13);
    if (i < 23) {
      ushort_t* nxt = S + (((i + 1) & 1) << 13);
      int k0n = (i + 1) * 32;
      stage16(Arow + k0n, nxt + wave * 512);
      stage16(Wrow + k0n, nxt + 4096 + wave * 512);
    }
    bf16x8 af[4], bfr[2];
#pragma unroll
    for (int mt = 0; mt < 4; ++mt)
      af[mt] = *(const bf16x8*)&cur[(wm * 64 + mt * 16 + l15) * 32 + quad * 8];
#pragma unroll
    for (int nt = 0; nt < 2; ++nt)
      bfr[nt] = *(const bf16x8*)&cur[4096 + (wn * 32 + nt * 16 + l15) * 32 + quad * 8];
#pragma unroll
    for (int mt = 0; mt < 4; ++mt)
#pragma unroll
      for (int nt = 0; nt < 2; ++nt)
        acc[mt][nt] = __builtin_amdgcn_mfma_f32_16x16x32_bf16(af[mt], bfr[nt], acc[mt][nt], 0, 0, 0);
    __syncthreads();
  }

  // ---- epilogue: acc -> LDS bf16 image (stride 136) -> coalesced dwordx4 stores ----
  const float scale = task == 0 ? CEXP : 1.0f;
#pragma unroll
  for (int mt = 0; mt < 4; ++mt)
#pragma unroll
    for (int nt = 0; nt < 2; ++nt) {
      int lr0 = wm * 64 + mt * 16 + quad * 4;
      int lc = wn * 32 + nt * 16 + l15;
#pragma unroll
      for (int r = 0; r < 4; ++r) {
        float bsv = (task == 2) ? bias[rowTile + lr0 + r] : bias[colTile + lc];
        S[(lr0 + r) * 136 + lc] = f2b((acc[mt][nt][r] + bsv) * scale);
      }
    }
  __syncthreads();

  {
    int row = tid >> 2;
    int segu = (tid & 3) * 32;
    bf16x8 v0 = *(const bf16x8*)&S[row * 136 + segu + 0];
    bf16x8 v1 = *(const bf16x8*)&S[row * 136 + segu + 8];
    bf16x8 v2 = *(const bf16x8*)&S[row * 136 + segu + 16];
    bf16x8 v3 = *(const bf16x8*)&S[row * 136 + segu + 24];
    if (task == 2) {
      int d = rowTile + row;
      ushort_t* gp = Vtb + (((size_t)b * NH + (d >> 6)) * DH + (d & 63)) * LPAD + colTile + segu;
      *(bf16x8*)(gp + 0) = v0;  *(bf16x8*)(gp + 8) = v1;
      *(bf16x8*)(gp + 16) = v2; *(bf16x8*)(gp + 24) = v3;
    } else {
      ushort_t* out = task == 0 ? Qb : Kb;
      const int Rows = task == 0 ? SEQ : LPAD;
      int colbase = colTile + segu;
      int h = colbase >> 6, dd = colbase & 63;
      ushort_t* gp = out + (((size_t)b * NH + h) * Rows + rowTile + row) * DH + dd;
      *(bf16x8*)(gp + 0) = v0;  *(bf16x8*)(gp + 8) = v1;
      *(bf16x8*)(gp + 16) = v2; *(bf16x8*)(gp + 24) = v3;
    }
  }
}

// Attention: single-barrier prefetch pipeline, 64-key tiles double-buffered (17 tiles,
// fully-padded tile 17 skipped). Block = 128 q rows, 4 waves x 32. Q pre-scaled.
// LDS: KV dbuf 32 KB + Ps 18.4 KB = 51.2 KB -> 3 blocks/CU.
__global__ __launch_bounds__(256, 3) void attn(const ushort_t* __restrict__ Q,
                                               const ushort_t* __restrict__ K,
                                               const ushort_t* __restrict__ Vt,
                                               float* __restrict__ Out) {
  // buf i at KV + i*8192: Ks @ +0 ([kk d-half][key64][32]), Vs @ +4096 ([kc key32][d64][32])
  __shared__ __align__(16) ushort_t KV[16384];
  __shared__ __align__(16) ushort_t Ps[4 * 2304];   // per wave: 32 rows * stride 72

  const int tid = threadIdx.x, wave = tid >> 6, lane = tid & 63;
  const int quad = lane >> 4, l15 = lane & 15;
  const int lrow4 = lane >> 2, lcol8 = (lane & 3) << 3;
  const int bh = blockIdx.x, qt = blockIdx.y;
  const int h = bh % NH, b = bh / NH;

  const ushort_t* Qp = Q + (((size_t)b * NH + h) * SEQ + qt * 128) * DH;
  const ushort_t* Kp = K + ((size_t)b * NH + h) * LPAD * DH;
  const ushort_t* Vp = Vt + ((size_t)b * NH + h) * DH * LPAD;
  ushort_t* Pw = Ps + wave * 2304;

  bf16x8 qf[2][2];
#pragma unroll
  for (int mt = 0; mt < 2; ++mt)
#pragma unroll
    for (int kk = 0; kk < 2; ++kk)
      qf[mt][kk] = *(const bf16x8*)&Qp[(wave * 32 + mt * 16 + l15) * DH + kk * 32 + quad * 8];

  bf16x8 ones8;
#pragma unroll
  for (int j = 0; j < 8; ++j) ones8[j] = (short)0x3f80;

  f32x4 ob[2][4] = {};
  f32x4 obl[2] = {};

  // staging lambda-equivalent: wave stages K chunks {wave, wave+4}, V chunks {wave, wave+4}
  // K chunk c: kk=c>>2, kg=c&3; key = key0 + kg*16 + lrow4, d = kk*32 + lcol8
  // V chunk c: kc=c>>2, dg=c&3; d = dg*16 + lrow4, key = key0 + kc*32 + lcol8
#define STAGE_KV(key0_, buf_)                                                        \
  {                                                                                  \
    _Pragma("unroll")                                                                \
    for (int s = 0; s < 2; ++s) {                                                    \
      int c = wave + s * 4;                                                          \
      int hi = c >> 2, lo = c & 3;                                                   \
      stage16(Kp + (size_t)((key0_) + lo * 16 + lrow4) * DH + hi * 32 + lcol8,       \
              (buf_) + c * 512);                                                     \
      stage16(Vp + (size_t)(lo * 16 + lrow4) * LPAD + (key0_) + hi * 32 + lcol8,     \
              (buf_) + 4096 + c * 512);                                              \
    }                                                                                \
  }

  STAGE_KV(0, KV)
  __syncthreads();

  for (int kt = 0; kt < 17; ++kt) {
    ushort_t* cur = KV + ((kt & 1) << 13);
    if (kt < 16) {
      ushort_t* nxt = KV + (((kt + 1) & 1) << 13);
      STAGE_KV((kt + 1) * 64, nxt)
    }

    // S = Q K^T : 32 q rows x 64 keys per wave
    f32x4 sc[2][4] = {};
#pragma unroll
    for (int kk = 0; kk < 2; ++kk)
#pragma unroll
      for (int nt = 0; nt < 4; ++nt) {
        bf16x8 kf = *(const bf16x8*)&cur[kk * 2048 + (nt * 16 + l15) * 32 + quad * 8];
#pragma unroll
        for (int mt = 0; mt < 2; ++mt)
          sc[mt][nt] = __builtin_amdgcn_mfma_f32_16x16x32_bf16(qf[mt][kk], kf, sc[mt][nt], 0, 0, 0);
      }

    // P = exp2(S) truncated to bf16; mask pad keys (>=1032) on tile 16.
    if (kt < 16) {
#pragma unroll
      for (int mt = 0; mt < 2; ++mt)
#pragma unroll
        for (int nt = 0; nt < 4; ++nt)
#pragma unroll
          for (int r = 0; r < 4; ++r) {
            union { float f; unsigned u; } cu;
            cu.f = EXP2F(sc[mt][nt][r]);
            Pw[(mt * 16 + quad * 4 + r) * 72 + nt * 16 + l15] = (ushort_t)(cu.u >> 16);
          }
    } else {
      bool valid0 = (l15 < 8);  // keys 1024..1031 are nt==0, l15<8
#pragma unroll
      for (int mt = 0; mt < 2; ++mt)
#pragma unroll
        for (int nt = 0; nt < 4; ++nt) {
          bool valid = (nt == 0) && valid0;
#pragma unroll
          for (int r = 0; r < 4; ++r) {
            union { float f; unsigned u; } cu;
            cu.f = valid ? EXP2F(sc[mt][nt][r]) : 0.f;
            Pw[(mt * 16 + quad * 4 + r) * 72 + nt * 16 + l15] = (ushort_t)(cu.u >> 16);
          }
        }
    }

    // O += P V ; l += P 1
#pragma unroll
    for (int kc = 0; kc < 2; ++kc) {
      bf16x8 pf[2];
#pragma unroll
      for (int mt = 0; mt < 2; ++mt)
        pf[mt] = *(const bf16x8*)&Pw[(mt * 16 + l15) * 72 + kc * 32 + quad * 8];
#pragma unroll
      for (int dt = 0; dt < 4; ++dt) {
        bf16x8 vf = *(const bf16x8*)&cur[4096 + kc * 2048 + (dt * 16 + l15) * 32 + quad * 8];
#pragma unroll
        for (int mt = 0; mt < 2; ++mt)
          ob[mt][dt] = __builtin_amdgcn_mfma_f32_16x16x32_bf16(pf[mt], vf, ob[mt][dt], 0, 0, 0);
      }
#pragma unroll
      for (int mt = 0; mt < 2; ++mt)
        obl[mt] = __builtin_amdgcn_mfma_f32_16x16x32_bf16(pf[mt], ones8, obl[mt], 0, 0, 0);
    }
    __syncthreads();
  }

#pragma unroll
  for (int mt = 0; mt < 2; ++mt) {
    int row0 = qt * 128 + wave * 32 + mt * 16 + quad * 4;
    f32x4 linv;
#pragma unroll
    for (int r = 0; r < 4; ++r) linv[r] = 1.0f / obl[mt][r];
#pragma unroll
    for (int dt = 0; dt < 4; ++dt) {
      int col = h * DH + dt * 16 + l15;
#pragma unroll
      for (int r = 0; r < 4; ++r)
        Out[((size_t)b * SEQ + row0 + r) * DMODEL + col] = ob[mt][dt][r] * linv[r];
    }
  }
}

extern "C" void kernel_launch(void* const* d_in, const int* in_sizes, int n_in,
                              void* d_out, int out_size, void* d_ws, size_t ws_size,
                              hipStream_t stream) {
  const float* hidden = (const float*)d_in[0];
  const float* memv   = (const float*)d_in[1];
  const float* Wq = (const float*)d_in[2];
  const float* bq = (const float*)d_in[3];
  const float* Wk = (const float*)d_in[4];
  const float* bk = (const float*)d_in[5];
  const float* Wv = (const float*)d_in[6];
  const float* bv = (const float*)d_in[7];
  float* out = (float*)d_out;

  char* ws = (char*)d_ws;
  size_t off = 0;
  ushort_t* Xm  = (ushort_t*)(ws + off); off += (size_t)BATCH * LPAD * DMODEL * 2;
  ushort_t* Wqb = (ushort_t*)(ws + off); off += (size_t)DMODEL * DMODEL * 2;
  ushort_t* Wkb = (ushort_t*)(ws + off); off += (size_t)DMODEL * DMODEL * 2;
  ushort_t* Wvb = (ushort_t*)(ws + off); off += (size_t)DMODEL * DMODEL * 2;
  ushort_t* Qb  = (ushort_t*)(ws + off); off += (size_t)BATCH * NH * SEQ * DH * 2;
  ushort_t* Kb  = (ushort_t*)(ws + off); off += (size_t)BATCH * NH * LPAD * DH * 2;
  ushort_t* Vtb = (ushort_t*)(ws + off);

  prep<<<dim3(8640), 256, 0, stream>>>(hidden, memv, Wq, Wk, Wv, Xm, Wqb, Wkb, Wvb);
  gemm_fused<<<dim3(1248), 512, 0, stream>>>(Xm, Wqb, Wkb, Wvb, bq, bk, bv, Qb, Kb, Vtb);
  attn<<<dim3(96, 8), 256, 0, stream>>>(Qb, Kb, Vtb, out);
}